// Round 4
// baseline (156.391 us; speedup 1.0000x reference)
//
#include <hip/hip_runtime.h>
#include <hip/hip_cooperative_groups.h>

namespace cg = cooperative_groups;

#define HW 512
#define D1_PITCH 1604   // dwords per d1 row: 513 entries * 3 + (513>>3) pad + slack

__device__ __forceinline__ float prelu(float x, float a) { return x >= 0.f ? x : a * x; }

// ---------------- Fused cooperative kernel, v3 ----------------
// 1024 blocks x 256 threads (4 blocks/CU, 16 waves/CU). Block = 4 rows x 512 cols.
// batch = bid>>7, h0 = (bid&127)*4. s kept in REGISTERS (24 floats/thread).
// Phase A: 5 shared d1 rows -> swizzled LDS (one barrier). Phase B: 8 px/thread.
// grid.sync, redundant deterministic gate per block, scale regs, float4 write.
__global__ __launch_bounds__(256, 4) void fused(
    const float* __restrict__ in1, const float* __restrict__ in2, const float* __restrict__ in3,
    const float* __restrict__ Wd, const float* __restrict__ bd, const float* __restrict__ ad,
    const float* __restrict__ Wu, const float* __restrict__ bu, const float* __restrict__ au,
    const float* __restrict__ Wc, const float* __restrict__ bc, const float* __restrict__ ag,
    float* __restrict__ out, float* __restrict__ ws)
{
    __shared__ float d1[5 * D1_PITCH];   // ~32 KB
    __shared__ float red[4][3];
    __shared__ float ybuf[3];

    const int tid   = threadIdx.x;
    const int bid   = blockIdx.x;
    const int batch = bid >> 7;
    const int h0    = (bid & 127) * 4;

    float wd[9], wu[9];
    #pragma unroll
    for (int k = 0; k < 9; k++) { wd[k] = Wd[k]; wu[k] = Wu[k]; }
    const float bd0 = bd[0], bd1 = bd[1], bd2 = bd[2];
    const float ad0 = ad[0], ad1 = ad[1], ad2 = ad[2];
    const float bu0 = bu[0], bu1 = bu[1], bu2 = bu[2];
    const float au0 = au[0], au1 = au[1], au2 = au[2];
    const float cu0 = prelu(bu0, au0), cu1 = prelu(bu1, au1), cu2 = prelu(bu2, au2);

    // ---- Phase A: d1 rows 0..4 (output rows h0..h0+4) into swizzled LDS ----
    #pragma unroll
    for (int dr = 0; dr < 5; ++dr) {
        const int gh = h0 + dr;
        const float* rowp = in1 + ((size_t)(batch * 1024 + 2 * gh) * 1024) * 3;
        for (int c = tid; c < 513; c += 256) {
            float v0 = -INFINITY, v1 = -INFINITY, v2 = -INFINITY;
            if (gh < HW && c < HW) {
                const float* p = rowp + 6 * c;     // pixel (2*gh, 2*c)
                const float x0 = p[0], x1 = p[1], x2 = p[2];
                v0 = prelu(x0 * wd[0] + x1 * wd[3] + x2 * wd[6] + bd0, ad0);
                v1 = prelu(x0 * wd[1] + x1 * wd[4] + x2 * wd[7] + bd1, ad1);
                v2 = prelu(x0 * wd[2] + x1 * wd[5] + x2 * wd[8] + bd2, ad2);
            }
            float* q = d1 + dr * D1_PITCH + c * 3 + (c >> 3);
            q[0] = v0; q[1] = v1; q[2] = v2;
        }
    }
    __syncthreads();

    // ---- Phase B: 8 consecutive px per thread, row = h0 + (tid>>6) ----
    const int lr = tid >> 6;
    const int h  = h0 + lr;
    const int w0 = (tid & 63) * 8;

    // in2: 6 float4 = 24 floats (px-major [j][c], flat = 3j+c)
    const float* in2p = in2 + ((size_t)(batch * HW + h) * HW + w0) * 3;
    float i2v[24];
    #pragma unroll
    for (int k = 0; k < 6; ++k)
        *reinterpret_cast<float4*>(&i2v[4 * k]) = reinterpret_cast<const float4*>(in2p)[k];

    // i3 candidates: ud[k] = max(cu, prelu(conv_up(in3[he/2, w0/2+k]))), k=0..4
    const int he = h + (h & 1);
    const bool heok = he < HW;
    const int w3 = w0 >> 1;
    float ud[5][3];
    #pragma unroll
    for (int k = 0; k < 5; ++k) {
        float u0 = cu0, u1 = cu1, u2 = cu2;
        if (heok && (w3 + k) < 256) {
            const float* p = in3 + ((size_t)(batch * 256 + (he >> 1)) * 256 + w3 + k) * 3;
            const float x0 = p[0], x1 = p[1], x2 = p[2];
            u0 = fmaxf(u0, prelu(x0 * wu[0] + x1 * wu[3] + x2 * wu[6] + bu0, au0));
            u1 = fmaxf(u1, prelu(x0 * wu[1] + x1 * wu[4] + x2 * wu[7] + bu1, au1));
            u2 = fmaxf(u2, prelu(x0 * wu[2] + x1 * wu[5] + x2 * wu[8] + bu2, au2));
        }
        ud[k][0] = u0; ud[k][1] = u1; ud[k][2] = u2;
    }

    // rolling 2x2 maxpool over swizzled d1 rows lr, lr+1
    const int baseA = lr * D1_PITCH;
    const int baseB = (lr + 1) * D1_PITCH;
    int idx0 = w0 * 3 + (w0 >> 3);
    float pA0 = d1[baseA + idx0], pA1 = d1[baseA + idx0 + 1], pA2 = d1[baseA + idx0 + 2];
    float pB0 = d1[baseB + idx0], pB1 = d1[baseB + idx0 + 1], pB2 = d1[baseB + idx0 + 2];

    float s[8][3];
    float sum0 = 0.f, sum1 = 0.f, sum2 = 0.f;
    #pragma unroll
    for (int j = 0; j < 8; ++j) {
        const int c  = w0 + j + 1;
        const int id = c * 3 + (c >> 3);
        const float cA0 = d1[baseA + id], cA1 = d1[baseA + id + 1], cA2 = d1[baseA + id + 2];
        const float cB0 = d1[baseB + id], cB1 = d1[baseB + id + 1], cB2 = d1[baseB + id + 2];
        const int uk = (j + 1) >> 1;
        const float s0 = fmaxf(fmaxf(pA0, cA0), fmaxf(pB0, cB0)) + i2v[3 * j + 0] + ud[uk][0];
        const float s1 = fmaxf(fmaxf(pA1, cA1), fmaxf(pB1, cB1)) + i2v[3 * j + 1] + ud[uk][1];
        const float s2 = fmaxf(fmaxf(pA2, cA2), fmaxf(pB2, cB2)) + i2v[3 * j + 2] + ud[uk][2];
        s[j][0] = s0; s[j][1] = s1; s[j][2] = s2;
        sum0 += s0; sum1 += s1; sum2 += s2;
        pA0 = cA0; pA1 = cA1; pA2 = cA2;
        pB0 = cB0; pB1 = cB1; pB2 = cB2;
    }

    // ---- deterministic block reduction -> ws[bid] ----
    #pragma unroll
    for (int off = 32; off > 0; off >>= 1) {
        sum0 += __shfl_down(sum0, off);
        sum1 += __shfl_down(sum1, off);
        sum2 += __shfl_down(sum2, off);
    }
    if ((tid & 63) == 0) { red[tid >> 6][0] = sum0; red[tid >> 6][1] = sum1; red[tid >> 6][2] = sum2; }
    __syncthreads();
    if (tid == 0) {
        ws[bid * 3 + 0] = red[0][0] + red[1][0] + red[2][0] + red[3][0];
        ws[bid * 3 + 1] = red[0][1] + red[1][1] + red[2][1] + red[3][1];
        ws[bid * 3 + 2] = red[0][2] + red[1][2] + red[2][2] + red[3][2];
        __threadfence();
    }

    cg::this_grid().sync();

    // ---- gate: redundant per block, fixed-tree deterministic ----
    if (tid < 64) {
        const float* pw = ws + batch * 128 * 3;
        float g0 = pw[tid * 3 + 0] + pw[(tid + 64) * 3 + 0];
        float g1 = pw[tid * 3 + 1] + pw[(tid + 64) * 3 + 1];
        float g2 = pw[tid * 3 + 2] + pw[(tid + 64) * 3 + 2];
        #pragma unroll
        for (int off = 32; off > 0; off >>= 1) {
            g0 += __shfl_down(g0, off);
            g1 += __shfl_down(g1, off);
            g2 += __shfl_down(g2, off);
        }
        if (tid == 0) {
            const float inv_n = 1.f / (float)(HW * HW);
            g0 *= inv_n; g1 *= inv_n; g2 *= inv_n;
            const float x0 = prelu(g0 * Wc[0] + g1 * Wc[3] + g2 * Wc[6] + bc[0], ag[0]);
            const float x1 = prelu(g0 * Wc[1] + g1 * Wc[4] + g2 * Wc[7] + bc[1], ag[1]);
            const float x2 = prelu(g0 * Wc[2] + g1 * Wc[5] + g2 * Wc[8] + bc[2], ag[2]);
            const float q0 = x0 * Wc[0] + x1 * Wc[3] + x2 * Wc[6] + bc[0];
            const float q1 = x0 * Wc[1] + x1 * Wc[4] + x2 * Wc[7] + bc[1];
            const float q2 = x0 * Wc[2] + x1 * Wc[5] + x2 * Wc[8] + bc[2];
            const float m  = fmaxf(q0, fmaxf(q1, q2));
            const float e0 = expf(q0 - m), e1 = expf(q1 - m), e2 = expf(q2 - m);
            const float inv = 1.f / (e0 + e1 + e2);
            ybuf[0] = e0 * inv; ybuf[1] = e1 * inv; ybuf[2] = e2 * inv;
        }
    }
    __syncthreads();
    const float ym0 = ybuf[0], ym1 = ybuf[1], ym2 = ybuf[2];
    const float ym[3] = { ym0, ym1, ym2 };

    // ---- scale registers, float4 write ----
    float* outp = out + ((size_t)(batch * HW + h) * HW + w0) * 3;
    #pragma unroll
    for (int k = 0; k < 6; ++k) {
        float4 v;
        v.x = s[(4 * k + 0) / 3][(4 * k + 0) % 3] * ym[(4 * k + 0) % 3];
        v.y = s[(4 * k + 1) / 3][(4 * k + 1) % 3] * ym[(4 * k + 1) % 3];
        v.z = s[(4 * k + 2) / 3][(4 * k + 2) % 3] * ym[(4 * k + 2) % 3];
        v.w = s[(4 * k + 3) / 3][(4 * k + 3) % 3] * ym[(4 * k + 3) % 3];
        reinterpret_cast<float4*>(outp)[k] = v;
    }
}

// ---------------- Fallback: proven 3-kernel path (39 us) ----------------
__global__ __launch_bounds__(256) void k1_compute_s(
    const float* __restrict__ in1, const float* __restrict__ in2, const float* __restrict__ in3,
    const float* __restrict__ Wd, const float* __restrict__ bd, const float* __restrict__ ad,
    const float* __restrict__ Wu, const float* __restrict__ bu, const float* __restrict__ au,
    float* __restrict__ s_out, float* __restrict__ partials)
{
    const int b  = blockIdx.z;
    const int h0 = blockIdx.y * 16, w0 = blockIdx.x * 16;
    const int tid = threadIdx.x;
    __shared__ float d1t[17][17][3];
    for (int idx = tid; idx < 17 * 17; idx += 256) {
        const int ty = idx / 17, tx = idx % 17;
        const int gh = h0 + ty, gw = w0 + tx;
        float v0 = -INFINITY, v1 = -INFINITY, v2 = -INFINITY;
        if (gh < HW && gw < HW) {
            const float* p = in1 + (((b * 1024 + 2 * gh) * 1024 + 2 * gw) * 3);
            const float x0 = p[0], x1 = p[1], x2 = p[2];
            v0 = prelu(x0 * Wd[0] + x1 * Wd[3] + x2 * Wd[6] + bd[0], ad[0]);
            v1 = prelu(x0 * Wd[1] + x1 * Wd[4] + x2 * Wd[7] + bd[1], ad[1]);
            v2 = prelu(x0 * Wd[2] + x1 * Wd[5] + x2 * Wd[8] + bd[2], ad[2]);
        }
        d1t[ty][tx][0] = v0; d1t[ty][tx][1] = v1; d1t[ty][tx][2] = v2;
    }
    __syncthreads();
    const int ty = tid >> 4, tx = tid & 15;
    const int h = h0 + ty, w = w0 + tx;
    float i1c0 = fmaxf(fmaxf(d1t[ty][tx][0], d1t[ty][tx + 1][0]), fmaxf(d1t[ty + 1][tx][0], d1t[ty + 1][tx + 1][0]));
    float i1c1 = fmaxf(fmaxf(d1t[ty][tx][1], d1t[ty][tx + 1][1]), fmaxf(d1t[ty + 1][tx][1], d1t[ty + 1][tx + 1][1]));
    float i1c2 = fmaxf(fmaxf(d1t[ty][tx][2], d1t[ty][tx + 1][2]), fmaxf(d1t[ty + 1][tx][2], d1t[ty + 1][tx + 1][2]));
    const float cu0 = prelu(bu[0], au[0]), cu1 = prelu(bu[1], au[1]), cu2 = prelu(bu[2], au[2]);
    float i3c0 = cu0, i3c1 = cu1, i3c2 = cu2;
    const int he = h + (h & 1), we = w + (w & 1);
    if (he < HW && we < HW) {
        const float* p = in3 + (((b * 256 + (he >> 1)) * 256 + (we >> 1)) * 3);
        const float x0 = p[0], x1 = p[1], x2 = p[2];
        i3c0 = fmaxf(i3c0, prelu(x0 * Wu[0] + x1 * Wu[3] + x2 * Wu[6] + bu[0], au[0]));
        i3c1 = fmaxf(i3c1, prelu(x0 * Wu[1] + x1 * Wu[4] + x2 * Wu[7] + bu[1], au[1]));
        i3c2 = fmaxf(i3c2, prelu(x0 * Wu[2] + x1 * Wu[5] + x2 * Wu[8] + bu[2], au[2]));
    }
    const int pix = ((b * HW + h) * HW + w) * 3;
    float s0 = i1c0 + in2[pix + 0] + i3c0;
    float s1 = i1c1 + in2[pix + 1] + i3c1;
    float s2 = i1c2 + in2[pix + 2] + i3c2;
    s_out[pix + 0] = s0; s_out[pix + 1] = s1; s_out[pix + 2] = s2;
    #pragma unroll
    for (int off = 32; off > 0; off >>= 1) {
        s0 += __shfl_down(s0, off); s1 += __shfl_down(s1, off); s2 += __shfl_down(s2, off);
    }
    __shared__ float red[4][3];
    const int lane = tid & 63, wave = tid >> 6;
    if (lane == 0) { red[wave][0] = s0; red[wave][1] = s1; red[wave][2] = s2; }
    __syncthreads();
    if (tid == 0) {
        const int pid = (b * 32 + blockIdx.y) * 32 + blockIdx.x;
        partials[pid * 3 + 0] = red[0][0] + red[1][0] + red[2][0] + red[3][0];
        partials[pid * 3 + 1] = red[0][1] + red[1][1] + red[2][1] + red[3][1];
        partials[pid * 3 + 2] = red[0][2] + red[1][2] + red[2][2] + red[3][2];
    }
}

__global__ __launch_bounds__(256) void k2_gate(
    const float* __restrict__ partials,
    const float* __restrict__ Wc, const float* __restrict__ bc, const float* __restrict__ ag,
    float* __restrict__ y)
{
    const int b = blockIdx.x;
    const int tid = threadIdx.x;
    float s0 = 0.f, s1 = 0.f, s2 = 0.f;
    for (int i = tid; i < 1024; i += 256) {
        const float* p = partials + (b * 1024 + i) * 3;
        s0 += p[0]; s1 += p[1]; s2 += p[2];
    }
    #pragma unroll
    for (int off = 32; off > 0; off >>= 1) {
        s0 += __shfl_down(s0, off); s1 += __shfl_down(s1, off); s2 += __shfl_down(s2, off);
    }
    __shared__ float red[4][3];
    const int lane = tid & 63, wave = tid >> 6;
    if (lane == 0) { red[wave][0] = s0; red[wave][1] = s1; red[wave][2] = s2; }
    __syncthreads();
    if (tid == 0) {
        const float inv_n = 1.f / (float)(HW * HW);
        const float g0 = (red[0][0] + red[1][0] + red[2][0] + red[3][0]) * inv_n;
        const float g1 = (red[0][1] + red[1][1] + red[2][1] + red[3][1]) * inv_n;
        const float g2 = (red[0][2] + red[1][2] + red[2][2] + red[3][2]) * inv_n;
        const float x0 = prelu(g0 * Wc[0] + g1 * Wc[3] + g2 * Wc[6] + bc[0], ag[0]);
        const float x1 = prelu(g0 * Wc[1] + g1 * Wc[4] + g2 * Wc[7] + bc[1], ag[1]);
        const float x2 = prelu(g0 * Wc[2] + g1 * Wc[5] + g2 * Wc[8] + bc[2], ag[2]);
        const float q0 = x0 * Wc[0] + x1 * Wc[3] + x2 * Wc[6] + bc[0];
        const float q1 = x0 * Wc[1] + x1 * Wc[4] + x2 * Wc[7] + bc[1];
        const float q2 = x0 * Wc[2] + x1 * Wc[5] + x2 * Wc[8] + bc[2];
        const float m = fmaxf(q0, fmaxf(q1, q2));
        const float e0 = expf(q0 - m), e1 = expf(q1 - m), e2 = expf(q2 - m);
        const float inv = 1.f / (e0 + e1 + e2);
        y[b * 3 + 0] = e0 * inv; y[b * 3 + 1] = e1 * inv; y[b * 3 + 2] = e2 * inv;
    }
}

__global__ __launch_bounds__(256) void k3_scale(float* __restrict__ out, const float* __restrict__ y)
{
    const int i = blockIdx.x * 256 + threadIdx.x;
    const int f = i * 4;
    const int b = f / (HW * HW * 3);
    const int c0 = f % 3;
    const float* yb = y + b * 3;
    const float m0 = yb[c0];
    const float m1 = yb[c0 == 2 ? 0 : c0 + 1];
    const float m2 = yb[c0 == 0 ? 2 : c0 - 1];
    float4 v = reinterpret_cast<float4*>(out)[i];
    v.x *= m0; v.y *= m1; v.z *= m2; v.w *= m0;
    reinterpret_cast<float4*>(out)[i] = v;
}

extern "C" void kernel_launch(void* const* d_in, const int* in_sizes, int n_in,
                              void* d_out, int out_size, void* d_ws, size_t ws_size,
                              hipStream_t stream)
{
    const float* in1 = (const float*)d_in[0];
    const float* in2 = (const float*)d_in[1];
    const float* in3 = (const float*)d_in[2];
    const float* Wd  = (const float*)d_in[3];
    const float* bd  = (const float*)d_in[4];
    const float* ad  = (const float*)d_in[5];
    const float* Wu  = (const float*)d_in[6];
    const float* bu  = (const float*)d_in[7];
    const float* au  = (const float*)d_in[8];
    const float* Wc  = (const float*)d_in[9];
    const float* bc  = (const float*)d_in[10];
    const float* ag  = (const float*)d_in[11];
    float* out = (float*)d_out;
    float* ws  = (float*)d_ws;

    void* args[] = { (void*)&in1, (void*)&in2, (void*)&in3,
                     (void*)&Wd, (void*)&bd, (void*)&ad,
                     (void*)&Wu, (void*)&bu, (void*)&au,
                     (void*)&Wc, (void*)&bc, (void*)&ag,
                     (void*)&out, (void*)&ws };
    hipError_t err = hipLaunchCooperativeKernel((const void*)fused, dim3(1024), dim3(256),
                                                args, 0, stream);
    if (err != hipSuccess) {
        float* partials = ws;
        float* y        = partials + 8192 * 3;
        k1_compute_s<<<dim3(32, 32, 8), 256, 0, stream>>>(in1, in2, in3, Wd, bd, ad, Wu, bu, au, out, partials);
        k2_gate<<<8, 256, 0, stream>>>(partials, Wc, bc, ag, y);
        k3_scale<<<6144, 256, 0, stream>>>(out, y);
    }
}

// Round 5
// 42.675 us; speedup vs baseline: 3.6647x; 3.6647x over previous
//
#include <hip/hip_runtime.h>

#define HW 512
#define D1_PITCH 197   // 65 px * 3 ch = 195 dwords + 2 pad; 197 % 32 = 5 -> 2-way banks (free)

__device__ __forceinline__ float prelu(float x, float a) { return x >= 0.f ? x : a * x; }

// K1: 16x64 output tile per 256-thread block. grid (8, 32, 8).
// Stages d1[17][65] in LDS (one barrier), computes s = i1+i2+i3 (4 px/thread),
// writes s to d_out (3x float4), per-block partial sums to ws (per-batch contiguous).
__global__ __launch_bounds__(256) void k1_compute_s(
    const float* __restrict__ in1, const float* __restrict__ in2, const float* __restrict__ in3,
    const float* __restrict__ Wd, const float* __restrict__ bd, const float* __restrict__ ad,
    const float* __restrict__ Wu, const float* __restrict__ bu, const float* __restrict__ au,
    float* __restrict__ s_out, float* __restrict__ partials)
{
    __shared__ float d1[17 * D1_PITCH];
    __shared__ float red[4][3];

    const int tid   = threadIdx.x;
    const int bx    = blockIdx.x;      // 0..7  col tile (64 px)
    const int by    = blockIdx.y;      // 0..31 row tile (16 px)
    const int batch = blockIdx.z;      // 0..7
    const int h0    = by * 16;
    const int w0b   = bx * 64;

    float wd[9], wu[9];
    #pragma unroll
    for (int k = 0; k < 9; k++) { wd[k] = Wd[k]; wu[k] = Wu[k]; }
    const float bd0 = bd[0], bd1 = bd[1], bd2 = bd[2];
    const float ad0 = ad[0], ad1 = ad[1], ad2 = ad[2];
    const float bu0 = bu[0], bu1 = bu[1], bu2 = bu[2];
    const float au0 = au[0], au1 = au[1], au2 = au[2];
    const float cu0 = prelu(bu0, au0), cu1 = prelu(bu1, au1), cu2 = prelu(bu2, au2);

    // ---- Phase A: stage d1 tile rows h0..h0+16, cols w0b..w0b+64 ----
    #pragma unroll
    for (int k = 0; k < 5; ++k) {
        const int e = k * 256 + tid;
        if (e < 17 * 65) {
            const int dr = e / 65, dc = e - dr * 65;
            const int gh = h0 + dr, gw = w0b + dc;
            float v0 = -INFINITY, v1 = -INFINITY, v2 = -INFINITY;
            if (gh < HW && gw < HW) {
                const float* p = in1 + ((size_t)((batch * 1024 + 2 * gh) * 1024 + 2 * gw)) * 3;
                const float x0 = p[0], x1 = p[1], x2 = p[2];
                v0 = prelu(x0 * wd[0] + x1 * wd[3] + x2 * wd[6] + bd0, ad0);
                v1 = prelu(x0 * wd[1] + x1 * wd[4] + x2 * wd[7] + bd1, ad1);
                v2 = prelu(x0 * wd[2] + x1 * wd[5] + x2 * wd[8] + bd2, ad2);
            }
            float* q = d1 + dr * D1_PITCH + dc * 3;
            q[0] = v0; q[1] = v1; q[2] = v2;
        }
    }
    __syncthreads();

    // ---- Phase B: 4 consecutive px per thread ----
    const int r  = tid >> 4;            // 0..15 local row
    const int cg = tid & 15;            // col group
    const int h  = h0 + r;
    const int w0 = w0b + cg * 4;        // global col of first px (even)

    // in2: 12 floats = 3 float4 (flat = 3*j + ch, base % 12 == 0)
    const float* in2p = in2 + ((size_t)((batch * HW + h) * HW + w0)) * 3;
    float i2v[12];
    #pragma unroll
    for (int k = 0; k < 3; ++k)
        *reinterpret_cast<float4*>(&i2v[4 * k]) = reinterpret_cast<const float4*>(in2p)[k];

    // i3 candidates ud[0..2]: in3 cols w0/2 .. w0/2+2 at row he/2
    const int he = h + (h & 1);
    const bool heok = he < HW;
    const int w3 = w0 >> 1;
    float ud[3][3];
    #pragma unroll
    for (int k = 0; k < 3; ++k) {
        float u0 = cu0, u1 = cu1, u2 = cu2;
        if (heok && (w3 + k) < 256) {
            const float* p = in3 + ((size_t)((batch * 256 + (he >> 1)) * 256 + w3 + k)) * 3;
            const float x0 = p[0], x1 = p[1], x2 = p[2];
            u0 = fmaxf(u0, prelu(x0 * wu[0] + x1 * wu[3] + x2 * wu[6] + bu0, au0));
            u1 = fmaxf(u1, prelu(x0 * wu[1] + x1 * wu[4] + x2 * wu[7] + bu1, au1));
            u2 = fmaxf(u2, prelu(x0 * wu[2] + x1 * wu[5] + x2 * wu[8] + bu2, au2));
        }
        ud[k][0] = u0; ud[k][1] = u1; ud[k][2] = u2;
    }

    // rolling 2x2 maxpool over d1 rows r, r+1, cols 4cg..4cg+4
    const int baseA = r * D1_PITCH + cg * 12;
    const int baseB = baseA + D1_PITCH;
    float pA0 = d1[baseA + 0], pA1 = d1[baseA + 1], pA2 = d1[baseA + 2];
    float pB0 = d1[baseB + 0], pB1 = d1[baseB + 1], pB2 = d1[baseB + 2];

    float s[4][3];
    float sum0 = 0.f, sum1 = 0.f, sum2 = 0.f;
    #pragma unroll
    for (int j = 0; j < 4; ++j) {
        const int o = 3 * (j + 1);
        const float cA0 = d1[baseA + o], cA1 = d1[baseA + o + 1], cA2 = d1[baseA + o + 2];
        const float cB0 = d1[baseB + o], cB1 = d1[baseB + o + 1], cB2 = d1[baseB + o + 2];
        const int uk = (j + 1) >> 1;
        const float s0 = fmaxf(fmaxf(pA0, cA0), fmaxf(pB0, cB0)) + i2v[3 * j + 0] + ud[uk][0];
        const float s1 = fmaxf(fmaxf(pA1, cA1), fmaxf(pB1, cB1)) + i2v[3 * j + 1] + ud[uk][1];
        const float s2 = fmaxf(fmaxf(pA2, cA2), fmaxf(pB2, cB2)) + i2v[3 * j + 2] + ud[uk][2];
        s[j][0] = s0; s[j][1] = s1; s[j][2] = s2;
        sum0 += s0; sum1 += s1; sum2 += s2;
        pA0 = cA0; pA1 = cA1; pA2 = cA2;
        pB0 = cB0; pB1 = cB1; pB2 = cB2;
    }

    // write s: 3x float4 (flat channel mapping is compile-time: m=4k+i -> s[m/3][m%3])
    float* outp = s_out + ((size_t)((batch * HW + h) * HW + w0)) * 3;
    #pragma unroll
    for (int k = 0; k < 3; ++k) {
        float4 v;
        v.x = s[(4 * k + 0) / 3][(4 * k + 0) % 3];
        v.y = s[(4 * k + 1) / 3][(4 * k + 1) % 3];
        v.z = s[(4 * k + 2) / 3][(4 * k + 2) % 3];
        v.w = s[(4 * k + 3) / 3][(4 * k + 3) % 3];
        reinterpret_cast<float4*>(outp)[k] = v;
    }

    // deterministic block reduction -> partials[(batch*32+by)*8+bx]
    #pragma unroll
    for (int off = 32; off > 0; off >>= 1) {
        sum0 += __shfl_down(sum0, off);
        sum1 += __shfl_down(sum1, off);
        sum2 += __shfl_down(sum2, off);
    }
    if ((tid & 63) == 0) { red[tid >> 6][0] = sum0; red[tid >> 6][1] = sum1; red[tid >> 6][2] = sum2; }
    __syncthreads();
    if (tid == 0) {
        const int pid = (batch * 32 + by) * 8 + bx;
        partials[pid * 3 + 0] = red[0][0] + red[1][0] + red[2][0] + red[3][0];
        partials[pid * 3 + 1] = red[0][1] + red[1][1] + red[2][1] + red[3][1];
        partials[pid * 3 + 2] = red[0][2] + red[1][2] + red[2][2] + red[3][2];
    }
}

// K2: gate (redundant per block, fixed-tree deterministic) + in-place scale.
// 1024 blocks x 256 threads, 8 px/thread.
__global__ __launch_bounds__(256) void k2_gate_scale(
    const float* __restrict__ partials,
    const float* __restrict__ Wc, const float* __restrict__ bc, const float* __restrict__ ag,
    float* __restrict__ out)
{
    __shared__ float ybuf[3];
    const int bid   = blockIdx.x;       // 0..1023
    const int batch = bid >> 7;
    const int chunk = bid & 127;
    const int tid   = threadIdx.x;

    if (tid < 64) {
        const float* pw = partials + batch * 256 * 3;
        float g0 = 0.f, g1 = 0.f, g2 = 0.f;
        #pragma unroll
        for (int k = 0; k < 4; ++k) {
            const float* p = pw + (tid + 64 * k) * 3;
            g0 += p[0]; g1 += p[1]; g2 += p[2];
        }
        #pragma unroll
        for (int off = 32; off > 0; off >>= 1) {
            g0 += __shfl_down(g0, off);
            g1 += __shfl_down(g1, off);
            g2 += __shfl_down(g2, off);
        }
        if (tid == 0) {
            const float inv_n = 1.f / (float)(HW * HW);
            g0 *= inv_n; g1 *= inv_n; g2 *= inv_n;
            const float x0 = prelu(g0 * Wc[0] + g1 * Wc[3] + g2 * Wc[6] + bc[0], ag[0]);
            const float x1 = prelu(g0 * Wc[1] + g1 * Wc[4] + g2 * Wc[7] + bc[1], ag[1]);
            const float x2 = prelu(g0 * Wc[2] + g1 * Wc[5] + g2 * Wc[8] + bc[2], ag[2]);
            const float q0 = x0 * Wc[0] + x1 * Wc[3] + x2 * Wc[6] + bc[0];
            const float q1 = x0 * Wc[1] + x1 * Wc[4] + x2 * Wc[7] + bc[1];
            const float q2 = x0 * Wc[2] + x1 * Wc[5] + x2 * Wc[8] + bc[2];
            const float m  = fmaxf(q0, fmaxf(q1, q2));
            const float e0 = expf(q0 - m), e1 = expf(q1 - m), e2 = expf(q2 - m);
            const float inv = 1.f / (e0 + e1 + e2);
            ybuf[0] = e0 * inv; ybuf[1] = e1 * inv; ybuf[2] = e2 * inv;
        }
    }
    __syncthreads();
    const float ym[3] = { ybuf[0], ybuf[1], ybuf[2] };

    // 8 px/thread = 24 floats = 6 float4, base float index % 3 == 0 -> static channels
    float* p = out + ((size_t)batch * 262144 + chunk * 2048 + tid * 8) * 3;
    #pragma unroll
    for (int k = 0; k < 6; ++k) {
        float4 v = reinterpret_cast<float4*>(p)[k];
        v.x *= ym[(4 * k + 0) % 3];
        v.y *= ym[(4 * k + 1) % 3];
        v.z *= ym[(4 * k + 2) % 3];
        v.w *= ym[(4 * k + 3) % 3];
        reinterpret_cast<float4*>(p)[k] = v;
    }
}

extern "C" void kernel_launch(void* const* d_in, const int* in_sizes, int n_in,
                              void* d_out, int out_size, void* d_ws, size_t ws_size,
                              hipStream_t stream)
{
    const float* in1 = (const float*)d_in[0];
    const float* in2 = (const float*)d_in[1];
    const float* in3 = (const float*)d_in[2];
    const float* Wd  = (const float*)d_in[3];
    const float* bd  = (const float*)d_in[4];
    const float* ad  = (const float*)d_in[5];
    const float* Wu  = (const float*)d_in[6];
    const float* bu  = (const float*)d_in[7];
    const float* au  = (const float*)d_in[8];
    const float* Wc  = (const float*)d_in[9];
    const float* bc  = (const float*)d_in[10];
    const float* ag  = (const float*)d_in[11];
    float* out = (float*)d_out;
    float* partials = (float*)d_ws;     // 2048 * 3 floats

    k1_compute_s<<<dim3(8, 32, 8), 256, 0, stream>>>(in1, in2, in3, Wd, bd, ad, Wu, bu, au, out, partials);
    k2_gate_scale<<<1024, 256, 0, stream>>>(partials, Wc, bc, ag, out);
}